// Round 5
// baseline (274.856 us; speedup 1.0000x reference)
//
#include <hip/hip_runtime.h>
#include <hip/hip_bf16.h>
#include <math.h>

#define B_  8
#define N_  4096
#define C_  512
#define H_  8
#define HD_ 64
#define M_  (B_*N_)        // 32768
#define K_  C_             // 512
#define D3_ (3*C_)         // 1536
#define SCALE_ 0.125f

using f32x4  = __attribute__((ext_vector_type(4))) float;
using bf16x8 = __attribute__((ext_vector_type(8))) short;

__device__ __forceinline__ unsigned short f2bf(float f) {
    unsigned int u = __builtin_bit_cast(unsigned int, f);
    u += 0x7FFFu + ((u >> 16) & 1u);   // RNE
    return (unsigned short)(u >> 16);
}
__device__ __forceinline__ float bf2f(unsigned short s) {
    unsigned int u = ((unsigned int)s) << 16;
    return __builtin_bit_cast(float, u);
}

__device__ __forceinline__ void gl_lds16(const void* g, void* l) {
    __builtin_amdgcn_global_load_lds(
        (const __attribute__((address_space(1))) unsigned int*)(g),
        (__attribute__((address_space(3))) unsigned int*)(l), 16, 0, 0);
}

// ---------------------------------------------------------------------------
// GEMM1 (m97 structure, PASS-verified) + fused alpha-pool partials.
// 1D grid 3072, XCD-swizzled: wgid = (flat&7)*384 + (flat>>3); mt=wgid/12,
// dt=wgid%12 -> each XCD gets 32 consecutive m-tiles x all 12 d-tiles, so an
// x-panel (128KB bf16) is fetched once and L2-hit 11x. Bijective: 3072%8==0.
// ---------------------------------------------------------------------------
__global__ __launch_bounds__(256, 2)
void k_gemm1(const unsigned short* __restrict__ Ag, const unsigned short* __restrict__ Bg,
             const float* __restrict__ Wq,
             float* __restrict__ outQ, unsigned short* __restrict__ outK,
             unsigned short* __restrict__ outV,
             float* __restrict__ pm1, float* __restrict__ ps1, float* __restrict__ pv1)
{
    __shared__ __align__(16) unsigned char lds[16384];   // A 8KB | B 8KB
    const int flat = blockIdx.x;
    const int wgid = (flat & 7) * 384 + (flat >> 3);
    const int m0 = (wgid / 12) * 128;
    const int d0 = (wgid % 12) * 128;
    const int t = threadIdx.x, lane = t & 63, w = t >> 6;
    const int wr = w >> 1, wc = w & 1;
    const int lrow = lane >> 2, lslot = lane & 3;
    const int fr = lane & 15, g = lane >> 4;

    f32x4 acc[4][4];
    #pragma unroll
    for (int i = 0; i < 4; ++i)
        #pragma unroll
        for (int j = 0; j < 4; ++j) acc[i][j] = (f32x4){0.f,0.f,0.f,0.f};

    for (int k0 = 0; k0 < K_; k0 += 32) {
        #pragma unroll
        for (int s = 0; s < 2; ++s) {
            const int seg = w*2 + s;
            const int row = seg*16 + lrow;
            const int ch  = lslot ^ ((row >> 1) & 3);
            gl_lds16(Ag + (size_t)(m0+row)*K_ + k0 + ch*8, lds + seg*1024);
            gl_lds16(Bg + (size_t)(d0+row)*K_ + k0 + ch*8, lds + 8192 + seg*1024);
        }
        __syncthreads();
        bf16x8 aF[4], bF[4];
        #pragma unroll
        for (int i = 0; i < 4; ++i) {
            const int r = wr*64 + i*16 + fr;
            const int sl = g ^ ((r >> 1) & 3);
            aF[i] = *(const bf16x8*)(lds + r*64 + sl*16);
        }
        #pragma unroll
        for (int j = 0; j < 4; ++j) {
            const int r = wc*64 + j*16 + fr;
            const int sl = g ^ ((r >> 1) & 3);
            bF[j] = *(const bf16x8*)(lds + 8192 + r*64 + sl*16);
        }
        #pragma unroll
        for (int i = 0; i < 4; ++i)
            #pragma unroll
            for (int j = 0; j < 4; ++j)
                acc[i][j] = __builtin_amdgcn_mfma_f32_16x16x32_bf16(aF[i], bF[j], acc[i][j], 0, 0, 0);
        __syncthreads();
    }

    // ---- output writes ----
    #pragma unroll
    for (int i = 0; i < 4; ++i)
        #pragma unroll
        for (int j = 0; j < 4; ++j) {
            const int trow = wr*64 + i*16 + g*4;
            const int tcol = wc*64 + j*16 + fr;
            const int d = d0 + tcol;
            #pragma unroll
            for (int p = 0; p < 4; ++p) {
                const size_t m = (size_t)(m0 + trow + p);
                const float vv = acc[i][j][p];
                if (d0 < C_)          outQ[m*C_ + d] = vv;
                else if (d0 < 2*C_)   outK[m*C_ + (d - C_)] = f2bf(vv);
                else                  outV[m*C_ + (d - 2*C_)] = f2bf(vv);
            }
        }

    // ---- fused alpha-pool partials (q-blocks only) ----
    if (d0 < C_) {
        const int head = (d0 >> 6) + wc;
        const int b = m0 >> 12;
        const int bh = b*8 + head;
        const int mchunk = (m0 & 4095) >> 7;
        const int chunk = mchunk*8 + wr*4 + g;      // 0..255
        float wqv[4];
        #pragma unroll
        for (int j = 0; j < 4; ++j) wqv[j] = Wq[head*HD_ + j*16 + fr] * SCALE_;

        float s[4][4];
        #pragma unroll
        for (int i = 0; i < 4; ++i)
            #pragma unroll
            for (int p = 0; p < 4; ++p) {
                float d = acc[i][0][p]*wqv[0] + acc[i][1][p]*wqv[1]
                        + acc[i][2][p]*wqv[2] + acc[i][3][p]*wqv[3];
                d += __shfl_xor(d, 1); d += __shfl_xor(d, 2);
                d += __shfl_xor(d, 4); d += __shfl_xor(d, 8);
                s[i][p] = d;
            }
        float mx = s[0][0];
        #pragma unroll
        for (int i = 0; i < 4; ++i)
            #pragma unroll
            for (int p = 0; p < 4; ++p) mx = fmaxf(mx, s[i][p]);
        float e[4][4]; float ssum = 0.f;
        #pragma unroll
        for (int i = 0; i < 4; ++i)
            #pragma unroll
            for (int p = 0; p < 4; ++p) { e[i][p] = __expf(s[i][p] - mx); ssum += e[i][p]; }
        #pragma unroll
        for (int j = 0; j < 4; ++j) {
            float pvj = 0.f;
            #pragma unroll
            for (int i = 0; i < 4; ++i)
                #pragma unroll
                for (int p = 0; p < 4; ++p) pvj = fmaf(e[i][p], acc[i][j][p], pvj);
            pv1[((size_t)bh*256 + chunk)*64 + j*16 + fr] = pvj;
        }
        if (fr == 0) { pm1[bh*256 + chunk] = mx; ps1[bh*256 + chunk] = ssum; }
    }
}

// beta pool with fused alpha-combine prologue: each block derives gq[bh][lane]
// from the 256 alpha partials (broadcast L2 reads), then single-pass online
// softmax-weighted sum over its 256-row k chunk. grid = 1024 (bh, 16 chunks).
__global__ __launch_bounds__(256)
void k_pool2(const unsigned short* __restrict__ kb, const float* __restrict__ w_k,
             const float* __restrict__ pm1, const float* __restrict__ ps1,
             const float* __restrict__ pv1,
             float* __restrict__ pm2, float* __restrict__ ps2, float* __restrict__ pv2)
{
    __shared__ float mred[4];
    __shared__ float sl[4][64];
    __shared__ float sred2[4];
    const int bid = blockIdx.x;
    const int bh = bid >> 4, ch = bid & 15;
    const int b = bh >> 3, h = bh & 7;
    const int t = threadIdx.x, lane = t & 63, wv = t >> 6;

    // ---- alpha combine: gq channel (lane) for this bh ----
    float am = -1e30f;
    for (int c = 0; c < 256; c += 4) {
        const float4 p4 = *(const float4*)(pm1 + bh*256 + c);
        am = fmaxf(am, fmaxf(fmaxf(p4.x, p4.y), fmaxf(p4.z, p4.w)));
    }
    float as = 0.f, gqv = 0.f;
    for (int c = 0; c < 256; ++c) {
        const float e = __expf(pm1[bh*256 + c] - am);
        as  = fmaf(ps1[bh*256 + c], e, as);
        gqv = fmaf(pv1[((size_t)bh*256 + c)*64 + lane], e, gqv);
    }
    gqv /= as;

    const float wk = w_k[h*64 + lane] * gqv * SCALE_;
    const unsigned short* base = kb + ((size_t)b*N_ + ch*256)*C_ + h*64 + lane;

    float mw = -1e30f, sw = 0.f, pvw = 0.f;
    for (int n0 = wv*4; n0 < 256; n0 += 16) {
        float x0 = bf2f(base[(size_t)(n0+0)*C_]);
        float x1 = bf2f(base[(size_t)(n0+1)*C_]);
        float x2 = bf2f(base[(size_t)(n0+2)*C_]);
        float x3 = bf2f(base[(size_t)(n0+3)*C_]);
        float s0 = x0*wk, s1 = x1*wk, s2 = x2*wk, s3 = x3*wk;
        #pragma unroll
        for (int off = 32; off; off >>= 1) {
            s0 += __shfl_xor(s0, off); s1 += __shfl_xor(s1, off);
            s2 += __shfl_xor(s2, off); s3 += __shfl_xor(s3, off);
        }
        const float mx = fmaxf(fmaxf(s0,s1), fmaxf(s2,s3));
        const float mn = fmaxf(mw, mx);
        const float f  = __expf(mw - mn);
        const float e0 = __expf(s0 - mn), e1 = __expf(s1 - mn);
        const float e2 = __expf(s2 - mn), e3 = __expf(s3 - mn);
        sw  = sw*f  + (e0+e1+e2+e3);
        pvw = pvw*f + e0*x0 + e1*x1 + e2*x2 + e3*x3;
        mw = mn;
    }
    if (lane == 0) mred[wv] = mw;
    __syncthreads();
    const float mb = fmaxf(fmaxf(mred[0],mred[1]), fmaxf(mred[2],mred[3]));
    const float f = __expf(mw - mb);
    sl[wv][lane] = pvw * f;
    if (lane == 0) sred2[wv] = sw * f;
    __syncthreads();
    if (t < 64) {
        pv2[(size_t)bid*64 + t] = sl[0][t]+sl[1][t]+sl[2][t]+sl[3][t];
        if (t == 0) ps2[bid] = sred2[0]+sred2[1]+sred2[2]+sred2[3];
        if (t == 1) pm2[bid] = mb;
    }
}

// fold: wpb[b][d][k] = bf16(w_proj[d][k] * gkf[b][k]); beta combine inline.
__global__ __launch_bounds__(256)
void k_fold(const float* __restrict__ wp, const float* __restrict__ pm2,
            const float* __restrict__ ps2, const float* __restrict__ pv2,
            unsigned short* __restrict__ wpb)
{
    const int i = blockIdx.x*256 + threadIdx.x;   // quad over [8][512][512]
    const int idx4 = i*4;
    const int b  = idx4 >> 18;
    const int wi = idx4 & 262143;
    const int k  = idx4 & 511;
    const int h  = k >> 6, hd = k & 63;
    const int bh = b*8 + h;

    float m = pm2[bh*16];
    #pragma unroll
    for (int c = 1; c < 16; ++c) m = fmaxf(m, pm2[bh*16 + c]);
    float s = 0.f, g0 = 0.f, g1 = 0.f, g2 = 0.f, g3 = 0.f;
    #pragma unroll
    for (int c = 0; c < 16; ++c) {
        const float e = __expf(pm2[bh*16 + c] - m);
        s = fmaf(ps2[bh*16 + c], e, s);
        const float4 pvv = *(const float4*)(pv2 + (size_t)(bh*16 + c)*64 + hd);
        g0 = fmaf(pvv.x, e, g0); g1 = fmaf(pvv.y, e, g1);
        g2 = fmaf(pvv.z, e, g2); g3 = fmaf(pvv.w, e, g3);
    }
    const float inv = 1.0f / s;
    const float4 wv4 = *(const float4*)(wp + wi);
    ushort4 r;
    r.x = f2bf(wv4.x * g0 * inv); r.y = f2bf(wv4.y * g1 * inv);
    r.z = f2bf(wv4.z * g2 * inv); r.w = f2bf(wv4.w * g3 * inv);
    ((ushort4*)wpb)[i] = r;
}

// GEMM2, XCD-swizzled (1024 blocks: 128/XCD; mt=wgid>>2, dt=wgid&3)
__global__ __launch_bounds__(256, 2)
void k_gemm2(const unsigned short* __restrict__ Ag, const unsigned short* __restrict__ Wpb,
             const float* __restrict__ bproj, float* __restrict__ out)
{
    __shared__ __align__(16) unsigned char lds[16384];
    const int flat = blockIdx.x;
    const int wgid = (flat & 7) * 128 + (flat >> 3);
    const int m0 = (wgid >> 2) * 128;
    const int d0 = (wgid & 3) * 128;
    const int b  = m0 >> 12;
    const unsigned short* Bg = Wpb + (size_t)b * C_ * C_;
    const int t = threadIdx.x, lane = t & 63, w = t >> 6;
    const int wr = w >> 1, wc = w & 1;
    const int lrow = lane >> 2, lslot = lane & 3;
    const int fr = lane & 15, g = lane >> 4;

    f32x4 acc[4][4];
    #pragma unroll
    for (int i = 0; i < 4; ++i)
        #pragma unroll
        for (int j = 0; j < 4; ++j) acc[i][j] = (f32x4){0.f,0.f,0.f,0.f};

    for (int k0 = 0; k0 < K_; k0 += 32) {
        #pragma unroll
        for (int s = 0; s < 2; ++s) {
            const int seg = w*2 + s;
            const int row = seg*16 + lrow;
            const int ch  = lslot ^ ((row >> 1) & 3);
            gl_lds16(Ag + (size_t)(m0+row)*K_ + k0 + ch*8, lds + seg*1024);
            gl_lds16(Bg + (size_t)(d0+row)*K_ + k0 + ch*8, lds + 8192 + seg*1024);
        }
        __syncthreads();
        bf16x8 aF[4], bF[4];
        #pragma unroll
        for (int i = 0; i < 4; ++i) {
            const int r = wr*64 + i*16 + fr;
            const int sl = g ^ ((r >> 1) & 3);
            aF[i] = *(const bf16x8*)(lds + r*64 + sl*16);
        }
        #pragma unroll
        for (int j = 0; j < 4; ++j) {
            const int r = wc*64 + j*16 + fr;
            const int sl = g ^ ((r >> 1) & 3);
            bF[j] = *(const bf16x8*)(lds + 8192 + r*64 + sl*16);
        }
        #pragma unroll
        for (int i = 0; i < 4; ++i)
            #pragma unroll
            for (int j = 0; j < 4; ++j)
                acc[i][j] = __builtin_amdgcn_mfma_f32_16x16x32_bf16(aF[i], bF[j], acc[i][j], 0, 0, 0);
        __syncthreads();
    }

    #pragma unroll
    for (int i = 0; i < 4; ++i)
        #pragma unroll
        for (int j = 0; j < 4; ++j) {
            const int trow = wr*64 + i*16 + g*4;
            const int tcol = wc*64 + j*16 + fr;
            const int d = d0 + tcol;
            const float bp = bproj[d];
            #pragma unroll
            for (int p = 0; p < 4; ++p) {
                const size_t off = (size_t)(m0 + trow + p)*C_ + d;
                out[off] = acc[i][j][p] + bp + out[off];
            }
        }
}

// merged fp32->bf16 convert for x and w_qkv
__global__ void k_cvt2(const float* __restrict__ a, const float* __restrict__ bsrc,
                       unsigned short* __restrict__ oa, unsigned short* __restrict__ ob,
                       int na4, int nb4)
{
    int i = blockIdx.x*256 + threadIdx.x;
    const int stride = gridDim.x*256;
    const int tot = na4 + nb4;
    for (; i < tot; i += stride) {
        if (i < na4) {
            const float4 f = ((const float4*)a)[i];
            ushort4 r; r.x = f2bf(f.x); r.y = f2bf(f.y); r.z = f2bf(f.z); r.w = f2bf(f.w);
            ((ushort4*)oa)[i] = r;
        } else {
            const int j = i - na4;
            const float4 f = ((const float4*)bsrc)[j];
            ushort4 r; r.x = f2bf(f.x); r.y = f2bf(f.y); r.z = f2bf(f.z); r.w = f2bf(f.w);
            ((ushort4*)ob)[j] = r;
        }
    }
}

extern "C" void kernel_launch(void* const* d_in, const int* in_sizes, int n_in,
                              void* d_out, int out_size, void* d_ws, size_t ws_size,
                              hipStream_t stream)
{
    (void)in_sizes; (void)n_in; (void)out_size; (void)ws_size;
    const float* x      = (const float*)d_in[0];
    const float* w_qkv  = (const float*)d_in[1];
    const float* w_proj = (const float*)d_in[2];
    const float* b_proj = (const float*)d_in[3];
    const float* w_q    = (const float*)d_in[4];
    const float* w_k    = (const float*)d_in[5];
    float* out = (float*)d_out;

    unsigned short* xb  = (unsigned short*)d_ws;          // [M,K]  33.5MB
    unsigned short* wqb = xb  + (size_t)M_*K_;            // [D3,K] 1.6MB
    unsigned short* kb  = wqb + (size_t)D3_*K_;           // [M,C]  33.5MB
    unsigned short* vb  = kb  + (size_t)M_*C_;            // [M,C]  33.5MB
    unsigned short* wpb = vb  + (size_t)M_*C_;            // [8,C,C] 4MB
    float* pm1 = (float*)(wpb + (size_t)8*C_*C_);         // [64,256]
    float* ps1 = pm1 + 64*256;
    float* pv1 = ps1 + 64*256;                            // [64,256,64] 4MB
    float* pm2 = pv1 + (size_t)64*256*64;                 // [1024]
    float* ps2 = pm2 + 1024;
    float* pv2 = ps2 + 1024;                              // [1024,64]

    k_cvt2<<<2048, 256, 0, stream>>>(x, w_qkv, xb, wqb, M_*K_/4, D3_*K_/4);

    k_gemm1<<<3072, 256, 0, stream>>>(xb, wqb, w_q, out, kb, vb, pm1, ps1, pv1);

    k_pool2<<<1024, 256, 0, stream>>>(kb, w_k, pm1, ps1, pv1, pm2, ps2, pv2);
    k_fold<<<2048, 256, 0, stream>>>(w_proj, pm2, ps2, pv2, wpb);

    k_gemm2<<<1024, 256, 0, stream>>>(vb, wpb, b_proj, out);
}